// Round 9
// baseline (112.022 us; speedup 1.0000x reference)
//
#include <hip/hip_runtime.h>

typedef unsigned int uint32;

namespace {
constexpr int CCH = 256;   // channels
constexpr int OUT = 7;     // output size
constexpr int S   = 14;    // OUT * SAMPLE_NUM
constexpr int NUM_ROIS = 1024;

constexpr int H0 = 200, W0 = 304;
constexpr int H1 = 100, W1 = 152;
constexpr int H2 = 50,  W2 = 76;
constexpr int H3 = 25,  W3 = 38;

constexpr int HW0 = H0 * W0;   // 60800
constexpr int HW1 = H1 * W1;   // 15200
constexpr int HW2 = H2 * W2;   // 3800
constexpr int HW3 = H3 * W3;   // 950

// transposed bf16 NHWC level sizes (in ushorts)
constexpr size_t US0 = (size_t)2 * HW0 * CCH;
constexpr size_t US1 = (size_t)2 * HW1 * CCH;
constexpr size_t US2 = (size_t)2 * HW2 * CCH;
constexpr size_t US3 = (size_t)2 * HW3 * CCH;

// hw-tiles of 512 per (batch, channel-quarter): chunk = 8 * ceil(HW/512)
constexpr int NT0 = (HW0 + 511) / 512;   // 119 (tail 384)
constexpr int NT1 = (HW1 + 511) / 512;   // 30  (tail 352)
constexpr int NT2 = (HW2 + 511) / 512;   // 8   (tail 216)
constexpr int NT3 = (HW3 + 511) / 512;   // 2   (HW%4!=0 -> slow path)
constexpr int GQ0 = 8 * NT0;             // 952
constexpr int GQ1 = 8 * NT1;             // 240
constexpr int GQ2 = 8 * NT2;             // 64
constexpr int GQ3 = 8 * NT3;             // 16

constexpr int LPAD = 516;  // words per c-pair row: 512 data + 4 pad (16B-mult)
}

__device__ __forceinline__ unsigned short f2bf(float f) {
    uint32 u = __float_as_uint(f);
    u += 0x7fffu + ((u >> 16) & 1u);          // round-to-nearest-even
    return (unsigned short)(u >> 16);
}
__device__ __forceinline__ uint32 pk(float a, float b) {
    return (uint32)f2bf(a) | ((uint32)f2bf(b) << 16);
}
__device__ __forceinline__ float blo(uint32 u) { return __uint_as_float(u << 16); }
__device__ __forceinline__ float bhi(uint32 u) { return __uint_as_float(u & 0xffff0000u); }

// ---- NCHW fp32 -> NHWC bf16 transpose, long-sequential-stream variant ------
// Tile: 512 contiguous hw x 64 channels (quarter). Each wave reads its 16
// channels as 2KB fully-dense sequential runs (2 x 1KB dwordx4 wave-loads per
// channel) -> 8x longer DRAM bursts per stream visit than prior variants.
// LDS: 32 c-pair rows of 512 packed b32, stride 516 words. Phase B: per hw
// row, 128B contiguous NHWC store (one full line, no RMW).
__global__ __launch_bounds__(256) void transpose_seq(
    const float* __restrict__ f0, const float* __restrict__ f1,
    const float* __restrict__ f2, const float* __restrict__ f3,
    unsigned short* __restrict__ o0, unsigned short* __restrict__ o1,
    unsigned short* __restrict__ o2, unsigned short* __restrict__ o3)
{
    __shared__ uint32 lds[32 * LPAD];   // 66 KB -> 2 blocks/CU
    int r = blockIdx.x;
    const float* in; unsigned short* op; int HW, NT;
    if (r < GQ0)                {                   in = f0; op = o0; HW = HW0; NT = NT0; }
    else if (r < GQ0+GQ1)       { r -= GQ0;         in = f1; op = o1; HW = HW1; NT = NT1; }
    else if (r < GQ0+GQ1+GQ2)   { r -= GQ0+GQ1;     in = f2; op = o2; HW = HW2; NT = NT2; }
    else                        { r -= GQ0+GQ1+GQ2; in = f3; op = o3; HW = HW3; NT = NT3; }
    const int b    = r / (4 * NT);
    const int rem  = r - b * 4 * NT;
    const int q    = rem / NT;               // channel quarter 0..3
    const int tile = rem - q * NT;
    const int hw0  = tile * 512;

    const int t = threadIdx.x;
    const int l = t & 63;
    const int w = t >> 6;

    const float* src = in + (size_t)(b * CCH + q * 64) * HW;
    const bool fast = ((HW & 3) == 0) && (hw0 + 512 <= HW);

    if (fast) {
        #pragma unroll
        for (int p = 0; p < 8; ++p) {
            const int cp = w * 8 + p;                 // c-pair 0..31
            const float* pa = src + (size_t)(2 * cp) * HW + hw0;
            const float* pb = pa + HW;
            const float4 A0 = *reinterpret_cast<const float4*>(pa + 4 * l);
            const float4 A1 = *reinterpret_cast<const float4*>(pa + 256 + 4 * l);
            const float4 B0 = *reinterpret_cast<const float4*>(pb + 4 * l);
            const float4 B1 = *reinterpret_cast<const float4*>(pb + 256 + 4 * l);
            uint32* d = &lds[cp * LPAD + 4 * l];
            *reinterpret_cast<uint4*>(d) =
                make_uint4(pk(A0.x, B0.x), pk(A0.y, B0.y), pk(A0.z, B0.z), pk(A0.w, B0.w));
            *reinterpret_cast<uint4*>(d + 256) =
                make_uint4(pk(A1.x, B1.x), pk(A1.y, B1.y), pk(A1.z, B1.z), pk(A1.w, B1.w));
        }
    } else {
        #pragma unroll 1
        for (int p = 0; p < 8; ++p) {
            const int cp = w * 8 + p;
            const float* pa = src + (size_t)(2 * cp) * HW;
            const float* pb = pa + HW;
            #pragma unroll 1
            for (int k = 0; k < 8; ++k) {
                const int idx = 64 * k + l;
                const int hw = hw0 + idx;
                float a = 0.0f, bb = 0.0f;
                if (hw < HW) { a = pa[hw]; bb = pb[hw]; }
                lds[cp * LPAD + idx] = pk(a, bb);
            }
        }
    }
    __syncthreads();

    // ---- Phase B: per hw row, 128B contiguous bf16 NHWC store ----
    {
        const int n  = min(512, HW - hw0);
        const int sc = t & 7;          // 16B subcol: c-pairs 4sc..4sc+3
        const int r0 = t >> 3;         // 0..31
        #pragma unroll
        for (int k = 0; k < 16; ++k) {
            const int row = r0 + 32 * k;
            const uint32 v0 = lds[(4 * sc + 0) * LPAD + row];
            const uint32 v1 = lds[(4 * sc + 1) * LPAD + row];
            const uint32 v2 = lds[(4 * sc + 2) * LPAD + row];
            const uint32 v3 = lds[(4 * sc + 3) * LPAD + row];
            if (row < n) {
                *reinterpret_cast<uint4*>(
                    op + ((size_t)b * HW + hw0 + row) * CCH + q * 64 + 8 * sc) =
                    make_uint4(v0, v1, v2, v3);
            }
        }
    }
}

// ---------------- gather from NHWC bf16 (unchanged, proven) -----------------
__global__ __launch_bounds__(256) void roi_gather_bf16(
    const unsigned short* __restrict__ w0, const unsigned short* __restrict__ w1,
    const unsigned short* __restrict__ w2, const unsigned short* __restrict__ w3,
    const float* __restrict__ rois, float* __restrict__ out)
{
    const int k = blockIdx.x;
    const int t = threadIdx.x;

    __shared__ float s_wlo[2][S];
    __shared__ float s_whi[2][S];
    __shared__ int   s_olo[2][S];   // offsets in uint2 units (y: W*64, x: 64)
    __shared__ int   s_ohi[2][S];
    __shared__ __align__(16) float s_out[25 * 260];

    const float rb  = rois[k*5+0];
    const float rx1 = rois[k*5+1];
    const float ry1 = rois[k*5+2];
    const float rx2 = rois[k*5+3];
    const float ry2 = rois[k*5+4];

    const float sc = sqrtf((rx2 - rx1 + 1.0f) * (ry2 - ry1 + 1.0f));
    int lvl = (int)floorf(log2f(sc * (1.0f/56.0f) + 1e-6f));
    lvl = lvl < 0 ? 0 : (lvl > 3 ? 3 : lvl);

    const unsigned short* fp; int H, W; float sp;
    if (lvl == 0)      { fp = w0; H = H0; W = W0; sp = 0.25f;    }
    else if (lvl == 1) { fp = w1; H = H1; W = W1; sp = 0.125f;   }
    else if (lvl == 2) { fp = w2; H = H2; W = W2; sp = 0.0625f;  }
    else               { fp = w3; H = H3; W = W3; sp = 0.03125f; }

    if (t < 2*S) {
        const int axis = (t >= S) ? 1 : 0;     // 0=y, 1=x
        const int i = axis ? (t - S) : t;
        const float lo = (axis ? rx1 : ry1) * sp;
        const float hi = (axis ? rx2 : ry2) * sp;
        const int dim  = axis ? W : H;
        const float len = fmaxf(hi - lo, 1.0f);
        const float bin = len * (1.0f / (float)S);
        const float v = lo + ((float)i + 0.5f) * bin;
        const bool valid = (v >= -1.0f) && (v <= (float)dim);
        float vc = fmaxf(v, 0.0f);
        int l = (int)floorf(vc);
        if (l >= dim - 1) { vc = (float)(dim - 1); l = dim - 1; }
        const int h = min(l + 1, dim - 1);
        const float frac = vc - (float)l;
        float wlo = 1.0f - frac;
        float whi = frac;
        if (!valid) { wlo = 0.0f; whi = 0.0f; }
        const int mul = axis ? 64 : W * 64;    // uint2 units
        s_wlo[axis][i] = wlo;
        s_whi[axis][i] = whi;
        s_olo[axis][i] = l * mul;
        s_ohi[axis][i] = h * mul;
    }
    __syncthreads();

    const int b = (int)rb;
    const int lane = t & 63;
    const int wv   = t >> 6;
    const uint2* __restrict__ base =
        reinterpret_cast<const uint2*>(fp) + (size_t)b * H * W * 64 + lane;
    float* __restrict__ ob = out + (size_t)k * CCH * (OUT * OUT);

    #pragma unroll
    for (int hf = 0; hf < 2; ++hf) {
        const int bb = hf ? 25 : 0;
        const int ne = hf ? 24 : 25;

        for (int bl = wv; bl < ne; bl += 4) {
            const int bin = bb + bl;
            const int oh = bin / 7;
            const int ow = bin - oh * 7;
            const int sy0 = oh * 2, sx0 = ow * 2;
            float a0 = 0.f, a1 = 0.f, a2 = 0.f, a3 = 0.f;
            #pragma unroll
            for (int dy = 0; dy < 2; ++dy) {
                const float hy = s_wlo[0][sy0 + dy];
                const float ly = s_whi[0][sy0 + dy];
                const int oyl = s_olo[0][sy0 + dy];
                const int oyh = s_ohi[0][sy0 + dy];
                #pragma unroll
                for (int dx = 0; dx < 2; ++dx) {
                    const float hx = s_wlo[1][sx0 + dx];
                    const float lx = s_whi[1][sx0 + dx];
                    const int oxl = s_olo[1][sx0 + dx];
                    const int oxh = s_ohi[1][sx0 + dx];
                    const uint2 qll = base[oyl + oxl];
                    const uint2 qlh = base[oyl + oxh];
                    const uint2 qhl = base[oyh + oxl];
                    const uint2 qhh = base[oyh + oxh];
                    const float wll = hy * hx, wlh = hy * lx;
                    const float whl = ly * hx, whh = ly * lx;
                    a0 += wll*blo(qll.x) + wlh*blo(qlh.x) + whl*blo(qhl.x) + whh*blo(qhh.x);
                    a1 += wll*bhi(qll.x) + wlh*bhi(qlh.x) + whl*bhi(qhl.x) + whh*bhi(qhh.x);
                    a2 += wll*blo(qll.y) + wlh*blo(qlh.y) + whl*blo(qhl.y) + whh*blo(qhh.y);
                    a3 += wll*bhi(qll.y) + wlh*bhi(qlh.y) + whl*bhi(qhl.y) + whh*bhi(qhh.y);
                }
            }
            float4 res = make_float4(a0*0.25f, a1*0.25f, a2*0.25f, a3*0.25f);
            *reinterpret_cast<float4*>(&s_out[bl * 260 + 4 * lane]) = res;
        }
        __syncthreads();

        #pragma unroll 1
        for (int j = 0; j < ne; ++j) {
            const int f = t + j * 256;
            const int c = f / ne;
            const int bl = f - c * ne;
            ob[c * (OUT*OUT) + bb + bl] = s_out[bl * 260 + c];
        }
        __syncthreads();
    }
}

// ---------------- fallback (direct NCHW fp32) if ws too small ---------------
__global__ __launch_bounds__(256) void roi_extract_direct(
    const float* __restrict__ f0, const float* __restrict__ f1,
    const float* __restrict__ f2, const float* __restrict__ f3,
    const float* __restrict__ rois, float* __restrict__ out)
{
    const int k = blockIdx.x;
    const int t = threadIdx.x;

    __shared__ float s_wlo[2][S];
    __shared__ float s_whi[2][S];
    __shared__ int   s_olo[2][S];
    __shared__ int   s_ohi[2][S];

    const float rb  = rois[k*5+0];
    const float rx1 = rois[k*5+1];
    const float ry1 = rois[k*5+2];
    const float rx2 = rois[k*5+3];
    const float ry2 = rois[k*5+4];

    const float sc = sqrtf((rx2 - rx1 + 1.0f) * (ry2 - ry1 + 1.0f));
    int lvl = (int)floorf(log2f(sc * (1.0f/56.0f) + 1e-6f));
    lvl = lvl < 0 ? 0 : (lvl > 3 ? 3 : lvl);

    const float* fp; int H, W; float sp;
    if (lvl == 0)      { fp = f0; H = H0; W = W0; sp = 0.25f;    }
    else if (lvl == 1) { fp = f1; H = H1; W = W1; sp = 0.125f;   }
    else if (lvl == 2) { fp = f2; H = H2; W = W2; sp = 0.0625f;  }
    else               { fp = f3; H = H3; W = W3; sp = 0.03125f; }

    if (t < 2*S) {
        const int axis = (t >= S) ? 1 : 0;
        const int i = axis ? (t - S) : t;
        const float lo = (axis ? rx1 : ry1) * sp;
        const float hi = (axis ? rx2 : ry2) * sp;
        const int dim  = axis ? W : H;
        const float len = fmaxf(hi - lo, 1.0f);
        const float bin = len * (1.0f / (float)S);
        const float v = lo + ((float)i + 0.5f) * bin;
        const bool valid = (v >= -1.0f) && (v <= (float)dim);
        float vc = fmaxf(v, 0.0f);
        int l = (int)floorf(vc);
        if (l >= dim - 1) { vc = (float)(dim - 1); l = dim - 1; }
        const int h = min(l + 1, dim - 1);
        const float frac = vc - (float)l;
        float wlo = 1.0f - frac;
        float whi = frac;
        if (!valid) { wlo = 0.0f; whi = 0.0f; }
        const int mul = axis ? 1 : W;
        s_wlo[axis][i] = wlo;
        s_whi[axis][i] = whi;
        s_olo[axis][i] = l * mul;
        s_ohi[axis][i] = h * mul;
    }
    __syncthreads();

    const int b = (int)rb;
    const float* __restrict__ base = fp + (size_t)(b * CCH + t) * (size_t)(H * W);
    float* __restrict__ obase = out + ((size_t)k * CCH + t) * (OUT * OUT);

    for (int oh = 0; oh < OUT; ++oh) {
        const int sy0 = oh * 2;
        const float hy0 = s_wlo[0][sy0],   ly0 = s_whi[0][sy0];
        const float hy1 = s_wlo[0][sy0+1], ly1 = s_whi[0][sy0+1];
        const int oyl0 = s_olo[0][sy0],   oyh0 = s_ohi[0][sy0];
        const int oyl1 = s_olo[0][sy0+1], oyh1 = s_ohi[0][sy0+1];
        #pragma unroll
        for (int ow = 0; ow < OUT; ++ow) {
            float acc = 0.0f;
            #pragma unroll
            for (int dx = 0; dx < 2; ++dx) {
                const int sx = ow * 2 + dx;
                const float hx = s_wlo[1][sx];
                const float lx = s_whi[1][sx];
                const int oxl = s_olo[1][sx];
                const int oxh = s_ohi[1][sx];
                acc += hy0 * (hx * base[oyl0 + oxl] + lx * base[oyl0 + oxh])
                     + ly0 * (hx * base[oyh0 + oxl] + lx * base[oyh0 + oxh])
                     + hy1 * (hx * base[oyl1 + oxl] + lx * base[oyl1 + oxh])
                     + ly1 * (hx * base[oyh1 + oxl] + lx * base[oyh1 + oxh]);
            }
            obase[oh * OUT + ow] = acc * 0.25f;
        }
    }
}

extern "C" void kernel_launch(void* const* d_in, const int* in_sizes, int n_in,
                              void* d_out, int out_size, void* d_ws, size_t ws_size,
                              hipStream_t stream) {
    const float* f0   = (const float*)d_in[0];
    const float* f1   = (const float*)d_in[1];
    const float* f2   = (const float*)d_in[2];
    const float* f3   = (const float*)d_in[3];
    const float* rois = (const float*)d_in[4];
    float* out = (float*)d_out;

    const size_t need_bytes = (US0 + US1 + US2 + US3) * sizeof(unsigned short);
    if (ws_size >= need_bytes) {
        unsigned short* ws0 = (unsigned short*)d_ws;
        unsigned short* ws1 = ws0 + US0;
        unsigned short* ws2 = ws1 + US1;
        unsigned short* ws3 = ws2 + US2;
        transpose_seq<<<GQ0 + GQ1 + GQ2 + GQ3, 256, 0, stream>>>(
            f0, f1, f2, f3, ws0, ws1, ws2, ws3);
        roi_gather_bf16<<<NUM_ROIS, 256, 0, stream>>>(ws0, ws1, ws2, ws3, rois, out);
    } else {
        roi_extract_direct<<<NUM_ROIS, 256, 0, stream>>>(f0, f1, f2, f3, rois, out);
    }
}